// Round 4
// baseline (79240.717 us; speedup 1.0000x reference)
//
#include <hip/hip_runtime.h>
#include <hip/hip_bf16.h>
#include <math.h>

#define BB 256
#define TT 256
#define FFE 263
#define CC 512
#define DD 256
#define NH 4
#define NLYR 4

#define EPI_BIAS 0
#define EPI_EMBED 1
#define EPI_RESID 2
#define EPI_GELU 3

// ---------------- lengths (valid_mask is a prefix mask; detect storage width) ----------------
__global__ __launch_bounds__(256) void k_lengths(const void* __restrict__ mask,
                                                 int* __restrict__ lengths) {
  int b = blockIdx.x, t = threadIdx.x;
  const unsigned char* m8 = (const unsigned char*)mask;
  // L>=4 always => mask[0][1] is "true". byte-storage => byte[1]!=0.
  // int32 (1 -> {01,00,00,00}) or float (1.0f -> {00,00,80,3F}) => byte[1]==0.
  bool is_byte = (m8[1] != 0);
  int v;
  if (is_byte) v = (m8[(size_t)b * TT + t] != 0);
  else         v = (((const int*)mask)[(size_t)b * TT + t] != 0);
  __shared__ int cnt;
  if (t == 0) cnt = 0;
  __syncthreads();
  unsigned long long bal = __ballot(v);
  if ((t & 63) == 0) atomicAdd(&cnt, __popcll(bal));
  __syncthreads();
  if (t == 0) lengths[b] = cnt;
}

// ---------------- cond MLP: condvec = silu(cond@w1+b1)@w2 + b2 ----------------
__global__ __launch_bounds__(256) void k_cond_mlp(const float* __restrict__ cond,
    const float* __restrict__ w1, const float* __restrict__ b1,
    const float* __restrict__ w2, const float* __restrict__ b2,
    float* __restrict__ condvec) {
  __shared__ float sc[CC];
  __shared__ float sz[DD];
  int b = blockIdx.x, j = threadIdx.x;
  sc[j]       = cond[(size_t)b * CC + j];
  sc[j + 256] = cond[(size_t)b * CC + 256 + j];
  __syncthreads();
  float acc = b1[j];
  #pragma unroll 8
  for (int c = 0; c < CC; c++) acc = fmaf(sc[c], w1[(size_t)c * DD + j], acc);
  sz[j] = acc * (1.0f / (1.0f + expf(-acc)));  // silu
  __syncthreads();
  float a2 = b2[j];
  #pragma unroll 8
  for (int d = 0; d < DD; d++) a2 = fmaf(sz[d], w2[(size_t)d * DD + j], a2);
  condvec[(size_t)b * DD + j] = a2;
}

// ---------------- LayerNorm (one wave per row, two-pass like the reference) ----------------
__global__ __launch_bounds__(256) void k_ln(const float* __restrict__ x,
    const float* __restrict__ g, const float* __restrict__ bta,
    float* __restrict__ y) {
  int row = blockIdx.x * 4 + (threadIdx.x >> 6);
  int lane = threadIdx.x & 63;
  float4 v = ((const float4*)(x + (size_t)row * DD))[lane];
  float s = v.x + v.y + v.z + v.w;
  #pragma unroll
  for (int o = 32; o > 0; o >>= 1) s += __shfl_xor(s, o);
  float m = s * (1.0f / DD);
  float dx = v.x - m, dy = v.y - m, dz = v.z - m, dw = v.w - m;
  float q = dx * dx + dy * dy + dz * dz + dw * dw;
  #pragma unroll
  for (int o = 32; o > 0; o >>= 1) q += __shfl_xor(q, o);
  float r = 1.0f / sqrtf(q * (1.0f / DD) + 1e-5f);
  float4 gg = ((const float4*)g)[lane];
  float4 bb = ((const float4*)bta)[lane];
  float4 o4;
  o4.x = dx * r * gg.x + bb.x;
  o4.y = dy * r * gg.y + bb.y;
  o4.z = dz * r * gg.z + bb.z;
  o4.w = dw * r * gg.w + bb.w;
  ((float4*)(y + (size_t)row * DD))[lane] = o4;
}

// ---------------- generic fp32 tiled GEMM: O = epi(A[M,K] @ W[K,N] + bias) ----------------
// EPI_EMBED uses global row ids (row0 + local row) to index pos_emb/condvec.
__global__ __launch_bounds__(256) void k_gemm(const float* __restrict__ A,
    const float* __restrict__ W, float* __restrict__ O,
    int M, int N, int K, int epi, int row0,
    const float* __restrict__ bias, const float* __restrict__ aux1,
    const float* __restrict__ aux2) {
  __shared__ float As[16][68];   // pad 68: conflict-free stores + aligned float4 reads
  __shared__ float Ws[16][64];
  int tid = threadIdx.x;
  int tx = tid & 15, ty = tid >> 4;
  int brow = blockIdx.x * 64, bcol = blockIdx.y * 64;
  float acc[4][4] = {{0.f}};
  int am = tid >> 4, ak = tid & 15;  // A staging: lane covers (row am+16i, k ak)
  int wn = tid & 63, wk0 = tid >> 6; // W staging
  for (int k0 = 0; k0 < K; k0 += 16) {
    #pragma unroll
    for (int i = 0; i < 4; i++) {
      int mm = am + i * 16;
      int kidx = k0 + ak;
      As[ak][mm] = (kidx < K) ? A[(size_t)(brow + mm) * K + kidx] : 0.0f;
    }
    #pragma unroll
    for (int i = 0; i < 4; i++) {
      int kk = wk0 + i * 4;
      int kidx = k0 + kk;
      Ws[kk][wn] = (kidx < K) ? W[(size_t)kidx * N + bcol + wn] : 0.0f;
    }
    __syncthreads();
    #pragma unroll
    for (int kk = 0; kk < 16; kk++) {
      float4 a4 = *((const float4*)&As[kk][ty * 4]);
      float4 w4 = *((const float4*)&Ws[kk][tx * 4]);
      float a[4] = {a4.x, a4.y, a4.z, a4.w};
      float w[4] = {w4.x, w4.y, w4.z, w4.w};
      #pragma unroll
      for (int i = 0; i < 4; i++)
        #pragma unroll
        for (int j = 0; j < 4; j++)
          acc[i][j] = fmaf(a[i], w[j], acc[i][j]);
    }
    __syncthreads();
  }
  #pragma unroll
  for (int i = 0; i < 4; i++) {
    int row = brow + ty * 4 + i;
    #pragma unroll
    for (int j = 0; j < 4; j++) {
      int col = bcol + tx * 4 + j;
      float v = acc[i][j] + bias[col];
      if (epi == EPI_EMBED) {
        int grow = row0 + row;
        int bb2 = grow >> 8, t2 = grow & 255;
        v += aux1[(size_t)t2 * DD + col] + aux2[(size_t)bb2 * DD + col];
      } else if (epi == EPI_RESID) {
        v += O[(size_t)row * N + col];
      } else if (epi == EPI_GELU) {
        v = 0.5f * v * (1.0f + erff(v * 0.70710678118654752f));
      }
      O[(size_t)row * N + col] = v;
    }
  }
}

// ---------------- attention: one block per (b_local, head); flash-style, online softmax ----------
// qkv/aout are chunk-local ([nb*TT, 768] / [nb*TT, 256]); lengths indexed by global batch.
__global__ __launch_bounds__(256) void k_attn(const float* __restrict__ qkv,
    float* __restrict__ aout, const int* __restrict__ lengths, int b_off) {
  __shared__ float Ks[64 * 65];
  __shared__ float Vs[64 * 65];
  __shared__ float qb[4][8][64];
  int bh = blockIdx.x;
  int bl = bh >> 2, hh = bh & 3;
  int L = lengths[b_off + bl];
  int tid = threadIdx.x;
  int wv = tid >> 6, lane = tid & 63;
  const size_t base = (size_t)bl * TT * 768;
  for (int qg = 0; qg < 8; qg++) {
    #pragma unroll
    for (int qi = 0; qi < 8; qi++) {
      int q = wv * 64 + qg * 8 + qi;
      qb[wv][qi][lane] = qkv[base + (size_t)q * 768 + hh * 64 + lane];
    }
    float m[8], l[8], oa[8];
    #pragma unroll
    for (int qi = 0; qi < 8; qi++) { m[qi] = -INFINITY; l[qi] = 0.f; oa[qi] = 0.f; }
    for (int kc = 0; kc < 4; kc++) {
      __syncthreads();  // protect Ks/Vs reuse
      for (int e = tid; e < 4096; e += 256) {
        int kt = e >> 6, d = e & 63;
        int gk = kc * 64 + kt;
        Ks[kt * 65 + d] = qkv[base + (size_t)gk * 768 + 256 + hh * 64 + d];
        Vs[kt * 65 + d] = qkv[base + (size_t)gk * 768 + 512 + hh * 64 + d];
      }
      __syncthreads();
      float kbias = ((kc * 64 + lane) < L) ? 0.0f : -1e9f;
      #pragma unroll
      for (int qi = 0; qi < 8; qi++) {
        float s = 0.f;
        #pragma unroll 16
        for (int d = 0; d < 64; d++)
          s = fmaf(qb[wv][qi][d], Ks[lane * 65 + d], s);
        s = s * 0.125f + kbias;
        float mx = s;
        #pragma unroll
        for (int o = 32; o > 0; o >>= 1) mx = fmaxf(mx, __shfl_xor(mx, o));
        float mnew = fmaxf(m[qi], mx);
        float scale = expf(m[qi] - mnew);   // first chunk: exp(-inf)=0
        float p = expf(s - mnew);
        float ps = p;
        #pragma unroll
        for (int o = 32; o > 0; o >>= 1) ps += __shfl_xor(ps, o);
        l[qi] = l[qi] * scale + ps;
        float o2 = oa[qi] * scale;
        #pragma unroll
        for (int t = 0; t < 64; t++)
          o2 = fmaf(__shfl(p, t), Vs[t * 65 + lane], o2);
        oa[qi] = o2;
        m[qi] = mnew;
      }
    }
    #pragma unroll
    for (int qi = 0; qi < 8; qi++) {
      int q = wv * 64 + qg * 8 + qi;
      aout[((size_t)(bl * TT + q)) * DD + hh * 64 + lane] = oa[qi] / l[qi];
    }
    __syncthreads();
  }
}

// ---------------- head: probs = sigmoid(h @ head_w + head_b) * valid ----------------
__global__ __launch_bounds__(256) void k_head(const float* __restrict__ h,
    const float* __restrict__ hw, const float* __restrict__ hb,
    const int* __restrict__ lengths, float* __restrict__ probs) {
  int row = blockIdx.x * 4 + (threadIdx.x >> 6);
  int lane = threadIdx.x & 63;
  float4 v = ((const float4*)(h + (size_t)row * DD))[lane];
  float4 w = ((const float4*)hw)[lane];
  float s = v.x * w.x + v.y * w.y + v.z * w.z + v.w * w.w;
  #pragma unroll
  for (int o = 32; o > 0; o >>= 1) s += __shfl_xor(s, o);
  if (lane == 0) {
    int b = row >> 8, t = row & 255;
    float logit = s + hb[0];
    float p = 1.0f / (1.0f + expf(-logit));
    probs[row] = (t < lengths[b]) ? p : 0.0f;
  }
}

// ---------------- endpoint-constrained budget top-k straight-through ----------------
__global__ __launch_bounds__(256) void k_select(const float* __restrict__ probs,
    const int* __restrict__ lengths, float* __restrict__ out) {
  __shared__ float sc[TT];
  int b = blockIdx.x, t = threadIdx.x;
  int L = lengths[b];
  bool valid = t < L;
  bool endp = (t == 0) || (t == L - 1);    // L >= 4 always
  float p = probs[b * TT + t];
  float pe = valid ? fmaxf(p, endp ? 1.0f : 0.0f) : 0.0f;
  bool inner = (t >= 1) && (t <= L - 2);
  sc[t] = (inner && valid) ? pe : -INFINITY;
  out[(size_t)b * TT + t] = pe;
  __syncthreads();
  float si = sc[t];
  int cnt = 0;
  for (int j = 0; j < TT; j++) {
    float sj = sc[j];
    cnt += ((sj > si) || (sj == si && j < t)) ? 1 : 0;   // stable descending rank
  }
  int budget = (int)rintf((float)L * 0.1f);              // matches jnp.round (RNE)
  budget = budget < 2 ? 2 : (budget > L ? L : budget);
  int ib = budget - 2; if (ib < 0) ib = 0;
  bool hard = (inner && valid && (cnt < ib)) || (endp && valid);
  out[(size_t)(BB * TT) + b * TT + t] = hard ? 1.0f : 0.0f;
}

extern "C" void kernel_launch(void* const* d_in, const int* in_sizes, int n_in,
                              void* d_out, int out_size, void* d_ws, size_t ws_size,
                              hipStream_t stream) {
  const float* motion  = (const float*)d_in[0];
  const void*  vmask   = d_in[1];
  const float* cond    = (const float*)d_in[2];
  const float* frame_w = (const float*)d_in[3];
  const float* frame_b = (const float*)d_in[4];
  const float* pos_emb = (const float*)d_in[5];
  const float* cond_w1 = (const float*)d_in[6];
  const float* cond_b1 = (const float*)d_in[7];
  const float* cond_w2 = (const float*)d_in[8];
  const float* cond_b2 = (const float*)d_in[9];
  const float* ln1_g   = (const float*)d_in[10];
  const float* ln1_b   = (const float*)d_in[11];
  const float* qkv_w   = (const float*)d_in[12];
  const float* qkv_b   = (const float*)d_in[13];
  const float* out_w   = (const float*)d_in[14];
  const float* out_b   = (const float*)d_in[15];
  const float* ln2_g   = (const float*)d_in[16];
  const float* ln2_b   = (const float*)d_in[17];
  const float* ff_w1   = (const float*)d_in[18];
  const float* ff_b1   = (const float*)d_in[19];
  const float* ff_w2   = (const float*)d_in[20];
  const float* ff_b2   = (const float*)d_in[21];
  const float* head_w  = (const float*)d_in[22];
  const float* head_b  = (const float*)d_in[23];
  float* out = (float*)d_out;

  // ---- workspace-adaptive layout (floats) ----
  // fixed: [lengths 256][condvec 64K][probs 64K][h 16.78M]  ~= 64.5 MB
  // per-chunk (nb batches = nb*256 rows): Abuf_c = rows*256, Ubuf_c = rows*1024
  int*   lengths = (int*)d_ws;
  float* Fw      = (float*)d_ws;
  float* condvec = Fw + 256;
  float* probs   = condvec + (size_t)BB * DD;
  float* h       = probs + (size_t)BB * TT;
  size_t base_floats = 256 + (size_t)BB * DD + (size_t)BB * TT + (size_t)BB * TT * DD;
  size_t ws_floats = ws_size / 4;
  size_t avail = (ws_floats > base_floats) ? (ws_floats - base_floats) : 0;
  // per chunk-batch cost: TT*(DD + 4*DD) = 256*1280 floats
  int cb = (int)(avail / ((size_t)TT * 1280));
  if (cb < 1) cb = 1;          // below this nothing fits; trust ws >= ~66 MB
  if (cb > BB) cb = BB;
  float* Abuf_c = h + (size_t)BB * TT * DD;               // cb*TT*DD floats
  float* Ubuf_c = Abuf_c + (size_t)cb * TT * DD;          // cb*TT*4*DD floats

  const int Mrow = BB * TT;

  k_lengths<<<BB, 256, 0, stream>>>(vmask, lengths);
  k_cond_mlp<<<BB, 256, 0, stream>>>(cond, cond_w1, cond_b1, cond_w2, cond_b2, condvec);
  // embed: full M (writes only h — always fits)
  k_gemm<<<dim3(Mrow / 64, DD / 64), 256, 0, stream>>>(
      motion, frame_w, h, Mrow, DD, FFE, EPI_EMBED, 0, frame_b, pos_emb, condvec);

  for (int i = 0; i < NLYR; i++) {
    for (int b0 = 0; b0 < BB; b0 += cb) {
      int nb = (BB - b0 < cb) ? (BB - b0) : cb;
      int nr = nb * TT;
      float* hc = h + (size_t)b0 * TT * DD;
      // LN1: h -> Abuf_c
      k_ln<<<nr / 4, 256, 0, stream>>>(hc, ln1_g + i * DD, ln1_b + i * DD, Abuf_c);
      // QKV: Abuf_c -> Ubuf_c [nr, 768]
      k_gemm<<<dim3(nr / 64, (3 * DD) / 64), 256, 0, stream>>>(
          Abuf_c, qkv_w + (size_t)i * DD * 3 * DD, Ubuf_c, nr, 3 * DD, DD, EPI_BIAS, 0,
          qkv_b + (size_t)i * 3 * DD, nullptr, nullptr);
      // attention: Ubuf_c -> Abuf_c (reuse; LN output dead)
      k_attn<<<nb * NH, 256, 0, stream>>>(Ubuf_c, Abuf_c, lengths, b0);
      // out-proj + residual: Abuf_c -> h
      k_gemm<<<dim3(nr / 64, DD / 64), 256, 0, stream>>>(
          Abuf_c, out_w + (size_t)i * DD * DD, hc, nr, DD, DD, EPI_RESID, 0,
          out_b + (size_t)i * DD, nullptr, nullptr);
      // LN2: h -> Abuf_c
      k_ln<<<nr / 4, 256, 0, stream>>>(hc, ln2_g + i * DD, ln2_b + i * DD, Abuf_c);
      // FF1 + gelu: Abuf_c -> Ubuf_c [nr, 1024]
      k_gemm<<<dim3(nr / 64, (4 * DD) / 64), 256, 0, stream>>>(
          Abuf_c, ff_w1 + (size_t)i * DD * 4 * DD, Ubuf_c, nr, 4 * DD, DD, EPI_GELU, 0,
          ff_b1 + (size_t)i * 4 * DD, nullptr, nullptr);
      // FF2 + residual: Ubuf_c -> h
      k_gemm<<<dim3(nr / 64, DD / 64), 256, 0, stream>>>(
          Ubuf_c, ff_w2 + (size_t)i * 4 * DD * DD, hc, nr, DD, 4 * DD, EPI_RESID, 0,
          ff_b2 + (size_t)i * DD, nullptr, nullptr);
    }
  }

  k_head<<<Mrow / 4, 256, 0, stream>>>(h, head_w, head_b, lengths, probs);
  k_select<<<BB, 256, 0, stream>>>(probs, lengths, out);
}

// Round 7
// 8912.434 us; speedup vs baseline: 8.8910x; 8.8910x over previous
//
#include <hip/hip_runtime.h>
#include <hip/hip_bf16.h>
#include <math.h>

#define BB 256
#define TT 256
#define FFE 263
#define CC 512
#define DD 256
#define NH 4
#define NLYR 4

#define EPI_BIAS 0
#define EPI_EMBED 1
#define EPI_RESID 2
#define EPI_GELU 3

// ---------------- lengths (valid_mask is a prefix mask; detect storage width) ----------------
__global__ __launch_bounds__(256) void k_lengths(const void* __restrict__ mask,
                                                 int* __restrict__ lengths) {
  int b = blockIdx.x, t = threadIdx.x;
  const unsigned char* m8 = (const unsigned char*)mask;
  // L>=4 always => mask[0][1] is "true". byte-storage => byte[1]!=0.
  // int32 (1 -> {01,00,00,00}) or float (1.0f -> {00,00,80,3F}) => byte[1]==0.
  bool is_byte = (m8[1] != 0);
  int v;
  if (is_byte) v = (m8[(size_t)b * TT + t] != 0);
  else         v = (((const int*)mask)[(size_t)b * TT + t] != 0);
  __shared__ int cnt;
  if (t == 0) cnt = 0;
  __syncthreads();
  unsigned long long bal = __ballot(v);
  if ((t & 63) == 0) atomicAdd(&cnt, __popcll(bal));
  __syncthreads();
  if (t == 0) lengths[b] = cnt;
}

// ---------------- cond MLP: condvec = silu(cond@w1+b1)@w2 + b2 ----------------
__global__ __launch_bounds__(256) void k_cond_mlp(const float* __restrict__ cond,
    const float* __restrict__ w1, const float* __restrict__ b1,
    const float* __restrict__ w2, const float* __restrict__ b2,
    float* __restrict__ condvec) {
  __shared__ float sc[CC];
  __shared__ float sz[DD];
  int b = blockIdx.x, j = threadIdx.x;
  sc[j]       = cond[(size_t)b * CC + j];
  sc[j + 256] = cond[(size_t)b * CC + 256 + j];
  __syncthreads();
  float acc = b1[j];
  #pragma unroll 8
  for (int c = 0; c < CC; c++) acc = fmaf(sc[c], w1[(size_t)c * DD + j], acc);
  sz[j] = acc * (1.0f / (1.0f + expf(-acc)));  // silu
  __syncthreads();
  float a2 = b2[j];
  #pragma unroll 8
  for (int d = 0; d < DD; d++) a2 = fmaf(sz[d], w2[(size_t)d * DD + j], a2);
  condvec[(size_t)b * DD + j] = a2;
}

// ---------------- LayerNorm (one wave per row, two-pass like the reference) ----------------
__global__ __launch_bounds__(256) void k_ln(const float* __restrict__ x,
    const float* __restrict__ g, const float* __restrict__ bta,
    float* __restrict__ y) {
  int row = blockIdx.x * 4 + (threadIdx.x >> 6);
  int lane = threadIdx.x & 63;
  float4 v = ((const float4*)(x + (size_t)row * DD))[lane];
  float s = v.x + v.y + v.z + v.w;
  #pragma unroll
  for (int o = 32; o > 0; o >>= 1) s += __shfl_xor(s, o);
  float m = s * (1.0f / DD);
  float dx = v.x - m, dy = v.y - m, dz = v.z - m, dw = v.w - m;
  float q = dx * dx + dy * dy + dz * dz + dw * dw;
  #pragma unroll
  for (int o = 32; o > 0; o >>= 1) q += __shfl_xor(q, o);
  float r = 1.0f / sqrtf(q * (1.0f / DD) + 1e-5f);
  float4 gg = ((const float4*)g)[lane];
  float4 bb = ((const float4*)bta)[lane];
  float4 o4;
  o4.x = dx * r * gg.x + bb.x;
  o4.y = dy * r * gg.y + bb.y;
  o4.z = dz * r * gg.z + bb.z;
  o4.w = dw * r * gg.w + bb.w;
  ((float4*)(y + (size_t)row * DD))[lane] = o4;
}

// ---------------- generic fp32 tiled GEMM: O = epi(A[M,K] @ W[K,N] + bias) ----------------
// EPI_EMBED uses global row ids (row0 + local row) to index pos_emb/condvec.
__global__ __launch_bounds__(256) void k_gemm(const float* __restrict__ A,
    const float* __restrict__ W, float* __restrict__ O,
    int M, int N, int K, int epi, int row0,
    const float* __restrict__ bias, const float* __restrict__ aux1,
    const float* __restrict__ aux2) {
  __shared__ float As[16][68];   // pad 68: conflict-free stores + aligned float4 reads
  __shared__ float Ws[16][64];
  int tid = threadIdx.x;
  int tx = tid & 15, ty = tid >> 4;
  int brow = blockIdx.x * 64, bcol = blockIdx.y * 64;
  float acc[4][4] = {{0.f}};
  int am = tid >> 4, ak = tid & 15;  // A staging: lane covers (row am+16i, k ak)
  int wn = tid & 63, wk0 = tid >> 6; // W staging
  for (int k0 = 0; k0 < K; k0 += 16) {
    #pragma unroll
    for (int i = 0; i < 4; i++) {
      int mm = am + i * 16;
      int kidx = k0 + ak;
      As[ak][mm] = (kidx < K) ? A[(size_t)(brow + mm) * K + kidx] : 0.0f;
    }
    #pragma unroll
    for (int i = 0; i < 4; i++) {
      int kk = wk0 + i * 4;
      int kidx = k0 + kk;
      Ws[kk][wn] = (kidx < K) ? W[(size_t)kidx * N + bcol + wn] : 0.0f;
    }
    __syncthreads();
    #pragma unroll
    for (int kk = 0; kk < 16; kk++) {
      float4 a4 = *((const float4*)&As[kk][ty * 4]);
      float4 w4 = *((const float4*)&Ws[kk][tx * 4]);
      float a[4] = {a4.x, a4.y, a4.z, a4.w};
      float w[4] = {w4.x, w4.y, w4.z, w4.w};
      #pragma unroll
      for (int i = 0; i < 4; i++)
        #pragma unroll
        for (int j = 0; j < 4; j++)
          acc[i][j] = fmaf(a[i], w[j], acc[i][j]);
    }
    __syncthreads();
  }
  #pragma unroll
  for (int i = 0; i < 4; i++) {
    int row = brow + ty * 4 + i;
    #pragma unroll
    for (int j = 0; j < 4; j++) {
      int col = bcol + tx * 4 + j;
      float v = acc[i][j] + bias[col];
      if (epi == EPI_EMBED) {
        int grow = row0 + row;
        int bb2 = grow >> 8, t2 = grow & 255;
        v += aux1[(size_t)t2 * DD + col] + aux2[(size_t)bb2 * DD + col];
      } else if (epi == EPI_RESID) {
        v += O[(size_t)row * N + col];
      } else if (epi == EPI_GELU) {
        v = 0.5f * v * (1.0f + erff(v * 0.70710678118654752f));
      }
      O[(size_t)row * N + col] = v;
    }
  }
}

// ---------------- attention v2: one block per (b_local, head, q-tile of 64) ----------------
// 256 threads: thread owns (q = tid>>2, quarter = tid&3) -> 16 head-dims of one query.
// Scores: 16-fma partial dots + 2x shfl_xor (4-lane reduce). Keys in 16-wide subtiles,
// p[16] in registers -> PV is 256 independent fmas (no serial cross-lane chain).
__global__ __launch_bounds__(256) void k_attn(const float* __restrict__ qkv,
    float* __restrict__ aout, const int* __restrict__ lengths, int b_off) {
  __shared__ float Ks[64][68];
  __shared__ float Vs[64][68];
  int bid = blockIdx.x;
  int qt = bid & 3;
  int hh = (bid >> 2) & 3;
  int bl = bid >> 4;
  int L = lengths[b_off + bl];
  int tid = threadIdx.x;
  int q = tid >> 2;
  int quarter = tid & 3;
  int gq = qt * 64 + q;
  const size_t base = (size_t)bl * TT * 768;

  float Qf[16];
  const float* qptr = qkv + base + (size_t)gq * 768 + hh * 64 + quarter * 16;
  #pragma unroll
  for (int i = 0; i < 4; i++) {
    float4 v4 = ((const float4*)qptr)[i];
    Qf[4 * i + 0] = v4.x; Qf[4 * i + 1] = v4.y;
    Qf[4 * i + 2] = v4.z; Qf[4 * i + 3] = v4.w;
  }

  float m = -INFINITY, l = 0.f;
  float o[16];
  #pragma unroll
  for (int i = 0; i < 16; i++) o[i] = 0.f;

  for (int kc = 0; kc < 4; kc++) {
    __syncthreads();
    // stage K/V chunk [64 keys][64 dims]; 1024 float4 each, 256 threads
    for (int e = tid; e < 1024; e += 256) {
      int kt = e >> 4, dq = e & 15;
      const float* kvp = qkv + base + (size_t)(kc * 64 + kt) * 768 + hh * 64 + dq * 4;
      *(float4*)&Ks[kt][dq * 4] = *(const float4*)(kvp + 256);
      *(float4*)&Vs[kt][dq * 4] = *(const float4*)(kvp + 512);
    }
    __syncthreads();
    #pragma unroll
    for (int sub = 0; sub < 4; sub++) {
      float p[16];
      float submax = -INFINITY;
      #pragma unroll
      for (int j = 0; j < 16; j++) {
        int kk = sub * 16 + j;
        float s = 0.f;
        #pragma unroll
        for (int i = 0; i < 16; i++)
          s = fmaf(Qf[i], Ks[kk][quarter * 16 + i], s);
        s += __shfl_xor(s, 1);
        s += __shfl_xor(s, 2);
        int gk = kc * 64 + kk;
        s = s * 0.125f + ((gk < L) ? 0.f : -1e9f);
        p[j] = s;
        submax = fmaxf(submax, s);
      }
      float mnew = fmaxf(m, submax);
      float scale = expf(m - mnew);       // first subtile: exp(-inf)=0
      float ps = 0.f;
      #pragma unroll
      for (int j = 0; j < 16; j++) { p[j] = expf(p[j] - mnew); ps += p[j]; }
      l = l * scale + ps;
      #pragma unroll
      for (int i = 0; i < 16; i++) o[i] *= scale;
      #pragma unroll
      for (int j = 0; j < 16; j++) {
        int kk = sub * 16 + j;
        #pragma unroll
        for (int i = 0; i < 16; i++)
          o[i] = fmaf(p[j], Vs[kk][quarter * 16 + i], o[i]);
      }
      m = mnew;
    }
  }

  float inv = 1.0f / l;
  float* optr = aout + ((size_t)(bl * TT + gq)) * DD + hh * 64 + quarter * 16;
  #pragma unroll
  for (int i = 0; i < 4; i++) {
    float4 v4;
    v4.x = o[4 * i + 0] * inv; v4.y = o[4 * i + 1] * inv;
    v4.z = o[4 * i + 2] * inv; v4.w = o[4 * i + 3] * inv;
    ((float4*)optr)[i] = v4;
  }
}

// ---------------- head: probs = sigmoid(h @ head_w + head_b) * valid ----------------
__global__ __launch_bounds__(256) void k_head(const float* __restrict__ h,
    const float* __restrict__ hw, const float* __restrict__ hb,
    const int* __restrict__ lengths, float* __restrict__ probs) {
  int row = blockIdx.x * 4 + (threadIdx.x >> 6);
  int lane = threadIdx.x & 63;
  float4 v = ((const float4*)(h + (size_t)row * DD))[lane];
  float4 w = ((const float4*)hw)[lane];
  float s = v.x * w.x + v.y * w.y + v.z * w.z + v.w * w.w;
  #pragma unroll
  for (int o = 32; o > 0; o >>= 1) s += __shfl_xor(s, o);
  if (lane == 0) {
    int b = row >> 8, t = row & 255;
    float logit = s + hb[0];
    float p = 1.0f / (1.0f + expf(-logit));
    probs[row] = (t < lengths[b]) ? p : 0.0f;
  }
}

// ---------------- endpoint-constrained budget top-k straight-through ----------------
__global__ __launch_bounds__(256) void k_select(const float* __restrict__ probs,
    const int* __restrict__ lengths, float* __restrict__ out) {
  __shared__ float sc[TT];
  int b = blockIdx.x, t = threadIdx.x;
  int L = lengths[b];
  bool valid = t < L;
  bool endp = (t == 0) || (t == L - 1);    // L >= 4 always
  float p = probs[b * TT + t];
  float pe = valid ? fmaxf(p, endp ? 1.0f : 0.0f) : 0.0f;
  bool inner = (t >= 1) && (t <= L - 2);
  sc[t] = (inner && valid) ? pe : -INFINITY;
  out[(size_t)b * TT + t] = pe;
  __syncthreads();
  float si = sc[t];
  int cnt = 0;
  for (int j = 0; j < TT; j++) {
    float sj = sc[j];
    cnt += ((sj > si) || (sj == si && j < t)) ? 1 : 0;   // stable descending rank
  }
  int budget = (int)rintf((float)L * 0.1f);              // matches jnp.round (RNE)
  budget = budget < 2 ? 2 : (budget > L ? L : budget);
  int ib = budget - 2; if (ib < 0) ib = 0;
  bool hard = (inner && valid && (cnt < ib)) || (endp && valid);
  out[(size_t)(BB * TT) + b * TT + t] = hard ? 1.0f : 0.0f;
}

extern "C" void kernel_launch(void* const* d_in, const int* in_sizes, int n_in,
                              void* d_out, int out_size, void* d_ws, size_t ws_size,
                              hipStream_t stream) {
  const float* motion  = (const float*)d_in[0];
  const void*  vmask   = d_in[1];
  const float* cond    = (const float*)d_in[2];
  const float* frame_w = (const float*)d_in[3];
  const float* frame_b = (const float*)d_in[4];
  const float* pos_emb = (const float*)d_in[5];
  const float* cond_w1 = (const float*)d_in[6];
  const float* cond_b1 = (const float*)d_in[7];
  const float* cond_w2 = (const float*)d_in[8];
  const float* cond_b2 = (const float*)d_in[9];
  const float* ln1_g   = (const float*)d_in[10];
  const float* ln1_b   = (const float*)d_in[11];
  const float* qkv_w   = (const float*)d_in[12];
  const float* qkv_b   = (const float*)d_in[13];
  const float* out_w   = (const float*)d_in[14];
  const float* out_b   = (const float*)d_in[15];
  const float* ln2_g   = (const float*)d_in[16];
  const float* ln2_b   = (const float*)d_in[17];
  const float* ff_w1   = (const float*)d_in[18];
  const float* ff_b1   = (const float*)d_in[19];
  const float* ff_w2   = (const float*)d_in[20];
  const float* ff_b2   = (const float*)d_in[21];
  const float* head_w  = (const float*)d_in[22];
  const float* head_b  = (const float*)d_in[23];
  float* out = (float*)d_out;

  // ---- workspace-adaptive layout (floats) ----
  // fixed: [lengths 256][condvec 64K][probs 64K][h 16.78M]  ~= 64.5 MB
  // per-chunk (nb batches = nb*256 rows): Abuf_c = rows*256, Ubuf_c = rows*1024
  int*   lengths = (int*)d_ws;
  float* Fw      = (float*)d_ws;
  float* condvec = Fw + 256;
  float* probs   = condvec + (size_t)BB * DD;
  float* h       = probs + (size_t)BB * TT;
  size_t base_floats = 256 + (size_t)BB * DD + (size_t)BB * TT + (size_t)BB * TT * DD;
  size_t ws_floats = ws_size / 4;
  size_t avail = (ws_floats > base_floats) ? (ws_floats - base_floats) : 0;
  // per chunk-batch cost: TT*(DD + 4*DD) = 256*1280 floats
  int cb = (int)(avail / ((size_t)TT * 1280));
  if (cb < 1) cb = 1;          // below this nothing fits; trust ws >= ~66 MB
  if (cb > BB) cb = BB;
  float* Abuf_c = h + (size_t)BB * TT * DD;               // cb*TT*DD floats
  float* Ubuf_c = Abuf_c + (size_t)cb * TT * DD;          // cb*TT*4*DD floats

  const int Mrow = BB * TT;

  k_lengths<<<BB, 256, 0, stream>>>(vmask, lengths);
  k_cond_mlp<<<BB, 256, 0, stream>>>(cond, cond_w1, cond_b1, cond_w2, cond_b2, condvec);
  // embed: full M (writes only h — always fits)
  k_gemm<<<dim3(Mrow / 64, DD / 64), 256, 0, stream>>>(
      motion, frame_w, h, Mrow, DD, FFE, EPI_EMBED, 0, frame_b, pos_emb, condvec);

  for (int i = 0; i < NLYR; i++) {
    for (int b0 = 0; b0 < BB; b0 += cb) {
      int nb = (BB - b0 < cb) ? (BB - b0) : cb;
      int nr = nb * TT;
      float* hc = h + (size_t)b0 * TT * DD;
      // LN1: h -> Abuf_c
      k_ln<<<nr / 4, 256, 0, stream>>>(hc, ln1_g + i * DD, ln1_b + i * DD, Abuf_c);
      // QKV: Abuf_c -> Ubuf_c [nr, 768]
      k_gemm<<<dim3(nr / 64, (3 * DD) / 64), 256, 0, stream>>>(
          Abuf_c, qkv_w + (size_t)i * DD * 3 * DD, Ubuf_c, nr, 3 * DD, DD, EPI_BIAS, 0,
          qkv_b + (size_t)i * 3 * DD, nullptr, nullptr);
      // attention: Ubuf_c -> Abuf_c (reuse; LN output dead)
      k_attn<<<nb * NH * 4, 256, 0, stream>>>(Ubuf_c, Abuf_c, lengths, b0);
      // out-proj + residual: Abuf_c -> h
      k_gemm<<<dim3(nr / 64, DD / 64), 256, 0, stream>>>(
          Abuf_c, out_w + (size_t)i * DD * DD, hc, nr, DD, DD, EPI_RESID, 0,
          out_b + (size_t)i * DD, nullptr, nullptr);
      // LN2: h -> Abuf_c
      k_ln<<<nr / 4, 256, 0, stream>>>(hc, ln2_g + i * DD, ln2_b + i * DD, Abuf_c);
      // FF1 + gelu: Abuf_c -> Ubuf_c [nr, 1024]
      k_gemm<<<dim3(nr / 64, (4 * DD) / 64), 256, 0, stream>>>(
          Abuf_c, ff_w1 + (size_t)i * DD * 4 * DD, Ubuf_c, nr, 4 * DD, DD, EPI_GELU, 0,
          ff_b1 + (size_t)i * 4 * DD, nullptr, nullptr);
      // FF2 + residual: Ubuf_c -> h
      k_gemm<<<dim3(nr / 64, DD / 64), 256, 0, stream>>>(
          Ubuf_c, ff_w2 + (size_t)i * 4 * DD * DD, hc, nr, DD, 4 * DD, EPI_RESID, 0,
          ff_b2 + (size_t)i * DD, nullptr, nullptr);
    }
  }

  k_head<<<Mrow / 4, 256, 0, stream>>>(h, head_w, head_b, lengths, probs);
  k_select<<<BB, 256, 0, stream>>>(probs, lengths, out);
}